// Round 8
// baseline (229.841 us; speedup 1.0000x reference)
//
#include <hip/hip_runtime.h>
#include <hip/hip_bf16.h>

// MultiheadAttention: B=2, S=2048, D=1024, H=16, dk=64.
// Inputs fp32, output fp32. Internals bf16 MFMA.
// r7 = r5 (proven, replay-stable) + qkv/vt merged into ONE dispatch using a
// SINGLE gemm template instantiation (runtime rowbias/permn/ostride flags so
// LDS stays 64 KB -> 2 blocks/CU; r6's 3-instantiation merge allocated 128 KB
// and raced). Inner GEMM loop byte-identical to r5: glds16 double-buffered,
// one __syncthreads per k-step, prefetch post-barrier.
// V is produced TRANSPOSED ([feature][token]) with tokens PERMUTED within each
// 64-token tile so the attention PV B-operand is one contiguous b128 LDS read.
// All LDS tiles: stride-64 rows, XOR swizzle col ^= ((row&7)<<3) (16B granule);
// glds staging uses PRE-SWIZZLED GLOBAL SOURCE (linear LDS dest).
// Attention: exp2 builtin (log2e folded into Q prescale), denominator via PV
// MFMA with B=ones, s_setprio(1) around MFMA clusters.

typedef __attribute__((ext_vector_type(8))) short short8;   // 8 bf16 = 4 VGPR (MFMA A/B frag)
typedef __attribute__((ext_vector_type(4))) float floatx4;  // MFMA C/D frag

#define D_MODEL 1024
#define SEQ 2048
#define NTOK 4096      // B*S
#define DK 64
#define NH 16
#define MAT 4194304    // NTOK*D_MODEL
#define WMAT 1048576   // D_MODEL*D_MODEL

static __device__ __forceinline__ unsigned short f2bf(float f) {
    unsigned int x = __float_as_uint(f);
    unsigned int r = x + 0x7fffu + ((x >> 16) & 1u);   // RNE
    return (unsigned short)(r >> 16);
}
static __device__ __forceinline__ float bf2f(unsigned short u) {
    return __uint_as_float(((unsigned int)u) << 16);
}
static __device__ __forceinline__ unsigned pk2(float x, float y) {
    __hip_bfloat162 h = __float22bfloat162_rn(make_float2(x, y));
    return *reinterpret_cast<unsigned*>(&h);
}
static __device__ __forceinline__ short8 cvt8(float4 f0, float4 f1) {
    union { unsigned u[4]; short8 s; } r;
    r.u[0] = pk2(f0.x, f0.y); r.u[1] = pk2(f0.z, f0.w);
    r.u[2] = pk2(f1.x, f1.y); r.u[3] = pk2(f1.z, f1.w);
    return r.s;
}
// token permutation within a 64-token tile: t=c*16+g*4+e -> g*16+c*4+e
static __device__ __forceinline__ int permtok(int t) {
    return ((t >> 2) & 3) * 16 + ((t >> 4) & 3) * 4 + (t & 3);
}
// async global->LDS, 16B per lane; LDS dest = wave-uniform base + lane*16
static __device__ __forceinline__ void glds16(const unsigned short* g, unsigned short* l) {
    __builtin_amdgcn_global_load_lds(
        (const __attribute__((address_space(1))) void*)g,
        (__attribute__((address_space(3))) void*)l, 16, 0, 0);
}

// ---------------------------------------------------------------------------
// fp32 -> bf16 conversion pass: xq,xk,xv (4M each) + wq,wk,wv,wo (1M each)
// ---------------------------------------------------------------------------
__global__ __launch_bounds__(256) void cvt7(
    const float* __restrict__ s0, const float* __restrict__ s1,
    const float* __restrict__ s2, const float* __restrict__ s3,
    const float* __restrict__ s4, const float* __restrict__ s5,
    const float* __restrict__ s6, unsigned short* __restrict__ dst) {
    const float* s; size_t doff; int n;
    switch (blockIdx.y) {
        case 0: s = s0; doff = 0;                          n = MAT;  break;
        case 1: s = s1; doff = (size_t)MAT;                n = MAT;  break;
        case 2: s = s2; doff = (size_t)2 * MAT;            n = MAT;  break;
        case 3: s = s3; doff = (size_t)3 * MAT;            n = WMAT; break;
        case 4: s = s4; doff = (size_t)3 * MAT + WMAT;     n = WMAT; break;
        case 5: s = s5; doff = (size_t)3 * MAT + 2 * WMAT; n = WMAT; break;
        default: s = s6; doff = (size_t)3 * MAT + 3 * WMAT; n = WMAT; break;
    }
    int idx = (blockIdx.x * 256 + threadIdx.x) * 8;
    if (idx >= n) return;
    float4 a = *(const float4*)(s + idx);
    float4 b = *(const float4*)(s + idx + 4);
    *(short8*)&dst[doff + idx] = cvt8(a, b);
}

// ---------------------------------------------------------------------------
// BMx128 NT GEMM, bf16 operands: out[m,n] = sum_k X[m,k]*W[n,k] + bias.
// Template: F32OUT, BM. Runtime: ostride, rowbias, permn (epilogue only) so
// one instantiation serves Q, K and V^T -> one 64 KB LDS allocation.
// Double-buffered LDS, glds16 staging (pre-swizzled source), one
// __syncthreads per k-step with prefetch issued post-barrier.
// ---------------------------------------------------------------------------
template <bool F32OUT, int BM>
static __device__ __forceinline__ void gemm_bb(const unsigned short* __restrict__ X,
                                               const unsigned short* __restrict__ W,
                                               const float* __restrict__ bias,
                                               void* __restrict__ outp,
                                               int m0, int n0,
                                               int ostride, bool rowbias, bool permn) {
    __shared__ __align__(16) unsigned short Asm[2][BM * 64];
    __shared__ __align__(16) unsigned short Bsm[2][128 * 64];
    constexpr int MF = BM / 32;          // m-fragments per wave
    constexpr int HALF = BM / 2;

    const int tid = threadIdx.x;
    const int lane = tid & 63;
    const int wv = tid >> 6;
    const int g = lane >> 4;
    const int lm = lane & 15;
    const int wr = wv >> 1;
    const int wc = wv & 1;
    const int rs = (lm & 7) << 3;          // read-side swizzle
    const int lr = lane >> 3;              // 0..7 : row within a glds group
    const int lc = lane & 7;               // 16B slot within row

    auto issue = [&](int k0, int p) {
#pragma unroll
        for (int i = 0; i < BM / 32; ++i) {
            const int r0 = wv * (BM / 4) + i * 8;
            const int row = r0 + lr;
            const int gcol = (lc ^ (row & 7)) << 3;
            glds16(&X[(size_t)(m0 + row) * 1024 + k0 + gcol], &Asm[p][r0 * 64]);
        }
#pragma unroll
        for (int i = 0; i < 4; ++i) {
            const int r0 = wv * 32 + i * 8;
            const int row = r0 + lr;
            const int gcol = (lc ^ (row & 7)) << 3;
            glds16(&W[(size_t)(n0 + row) * 1024 + k0 + gcol], &Bsm[p][r0 * 64]);
        }
    };

    floatx4 acc[MF][4];
#pragma unroll
    for (int mi = 0; mi < MF; ++mi)
#pragma unroll
        for (int ni = 0; ni < 4; ++ni)
            acc[mi][ni] = (floatx4){0.f, 0.f, 0.f, 0.f};

    issue(0, 0);
    for (int k0 = 0, it = 0; k0 < 1024; k0 += 64, ++it) {
        const int p = it & 1;
        __syncthreads();                         // vmcnt drain: tile it in LDS, all waves
        if (k0 + 64 < 1024) issue(k0 + 64, p ^ 1);   // prefetch lands during compute
#pragma unroll
        for (int ks = 0; ks < 64; ks += 32) {
            short8 af[MF], bfr[4];
#pragma unroll
            for (int mi = 0; mi < MF; ++mi)
                af[mi] = *(const short8*)&Asm[p][(wr * HALF + mi * 16 + lm) * 64 +
                                                ((ks + g * 8) ^ rs)];
#pragma unroll
            for (int ni = 0; ni < 4; ++ni)
                bfr[ni] = *(const short8*)&Bsm[p][(wc * 64 + ni * 16 + lm) * 64 +
                                                 ((ks + g * 8) ^ rs)];
#pragma unroll
            for (int mi = 0; mi < MF; ++mi)
#pragma unroll
                for (int ni = 0; ni < 4; ++ni)
                    acc[mi][ni] = __builtin_amdgcn_mfma_f32_16x16x32_bf16(
                        af[mi], bfr[ni], acc[mi][ni], 0, 0, 0);
        }
    }

    float cb[4];
#pragma unroll
    for (int ni = 0; ni < 4; ++ni)
        cb[ni] = rowbias ? 0.f : bias[n0 + wc * 64 + ni * 16 + lm];
#pragma unroll
    for (int mi = 0; mi < MF; ++mi)
#pragma unroll
        for (int r = 0; r < 4; ++r) {
            int rowg = m0 + wr * HALF + mi * 16 + g * 4 + r;
            float rb = rowbias ? bias[rowg] : 0.f;
#pragma unroll
            for (int ni = 0; ni < 4; ++ni) {
                int colg = n0 + wc * 64 + ni * 16 + lm;
                if (permn) colg = (colg & ~63) | permtok(colg & 63);
                float val = acc[mi][ni][r] + (rowbias ? rb : cb[ni]);
                if (F32OUT)
                    ((float*)outp)[(size_t)rowg * ostride + colg] = val;
                else
                    ((unsigned short*)outp)[(size_t)rowg * ostride + colg] = f2bf(val);
            }
        }
}

// Merged projections (one instantiation, runtime flags):
//   z=0: Q  = Xq @ Wq^T + bq          (m=tokens, n=features)
//   z=1: K  = Xk @ Wk^T + bk
//   z=2: VT = (Wv @ Xv^T)^perm + bv   (m=features, n=tokens, rowbias+permn)
__global__ __launch_bounds__(256) void proj_gemm_b(
    const unsigned short* __restrict__ Xb, const unsigned short* __restrict__ Wb,
    const float* __restrict__ bq, const float* __restrict__ bk,
    const float* __restrict__ bv, unsigned short* __restrict__ QK,
    unsigned short* __restrict__ VT) {
    const int z = blockIdx.z;
    const int bid = blockIdx.x;            // 0..255
    if (z == 0)
        gemm_bb<false, 128>(Xb, Wb, bq, QK,
                            (bid >> 3) * 128, (bid & 7) * 128, 1024, false, false);
    else if (z == 1)
        gemm_bb<false, 128>(Xb + (size_t)MAT, Wb + (size_t)WMAT, bk,
                            QK + (size_t)MAT,
                            (bid >> 3) * 128, (bid & 7) * 128, 1024, false, false);
    else
        gemm_bb<false, 128>(Wb + (size_t)2 * WMAT, Xb + (size_t)2 * MAT, bv, VT,
                            (bid & 7) * 128, (bid >> 3) * 128, 4096, true, true);
}

__global__ __launch_bounds__(256) void out_gemm_b(
    const unsigned short* __restrict__ ctx, const unsigned short* __restrict__ Wo,
    const float* __restrict__ bo, float* __restrict__ out) {
    gemm_bb<true, 64>(ctx, Wo, bo, out, blockIdx.y * 64, blockIdx.x * 128,
                      1024, false, false);
}

// ---------------- fallback path (fp32 staging), used if ws too small --------
template <bool ROWBIAS, bool PERMN, int OSTRIDE>
static __device__ __forceinline__ void gemm128_f(const float* __restrict__ X,
                                                 const float* __restrict__ W,
                                                 const float* __restrict__ bias,
                                                 unsigned short* __restrict__ out) {
    __shared__ __align__(16) unsigned short Asm[128 * 72];
    __shared__ __align__(16) unsigned short Bsm[128 * 72];
    const int tid = threadIdx.x;
    const int lane = tid & 63;
    const int wv = tid >> 6;
    const int g = lane >> 4;
    const int lm = lane & 15;
    const int wr = wv >> 1;
    const int wc = wv & 1;
    const int m0 = blockIdx.y * 128;
    const int n0 = blockIdx.x * 128;
    floatx4 acc[4][4];
#pragma unroll
    for (int mi = 0; mi < 4; ++mi)
#pragma unroll
        for (int ni = 0; ni < 4; ++ni)
            acc[mi][ni] = (floatx4){0.f, 0.f, 0.f, 0.f};
    for (int k0 = 0; k0 < 1024; k0 += 64) {
#pragma unroll
        for (int i = 0; i < 4; ++i) {
            int idx = tid + i * 256;
            int row = idx >> 3;
            int col = (idx & 7) << 3;
            const float* sa = &X[(size_t)(m0 + row) * 1024 + k0 + col];
            *(short8*)&Asm[row * 72 + col] = cvt8(*(const float4*)sa, *(const float4*)(sa + 4));
            const float* sb = &W[(size_t)(n0 + row) * 1024 + k0 + col];
            *(short8*)&Bsm[row * 72 + col] = cvt8(*(const float4*)sb, *(const float4*)(sb + 4));
        }
        __syncthreads();
#pragma unroll
        for (int ks = 0; ks < 64; ks += 32) {
            short8 af[4], bfr[4];
#pragma unroll
            for (int mi = 0; mi < 4; ++mi)
                af[mi] = *(const short8*)&Asm[(wr * 64 + mi * 16 + lm) * 72 + ks + g * 8];
#pragma unroll
            for (int ni = 0; ni < 4; ++ni)
                bfr[ni] = *(const short8*)&Bsm[(wc * 64 + ni * 16 + lm) * 72 + ks + g * 8];
#pragma unroll
            for (int mi = 0; mi < 4; ++mi)
#pragma unroll
                for (int ni = 0; ni < 4; ++ni)
                    acc[mi][ni] = __builtin_amdgcn_mfma_f32_16x16x32_bf16(
                        af[mi], bfr[ni], acc[mi][ni], 0, 0, 0);
        }
        __syncthreads();
    }
    float cb[4];
#pragma unroll
    for (int ni = 0; ni < 4; ++ni)
        cb[ni] = ROWBIAS ? 0.f : bias[n0 + wc * 64 + ni * 16 + lm];
#pragma unroll
    for (int mi = 0; mi < 4; ++mi)
#pragma unroll
        for (int r = 0; r < 4; ++r) {
            int rowg = m0 + wr * 64 + mi * 16 + g * 4 + r;
            float rb = ROWBIAS ? bias[rowg] : 0.f;
#pragma unroll
            for (int ni = 0; ni < 4; ++ni) {
                int colg = n0 + wc * 64 + ni * 16 + lm;
                if (PERMN) colg = (colg & ~63) | permtok(colg & 63);
                out[(size_t)rowg * OSTRIDE + colg] =
                    f2bf(acc[mi][ni][r] + (ROWBIAS ? rb : cb[ni]));
            }
        }
}

__global__ __launch_bounds__(256) void qkv_gemm_f(
    const float* __restrict__ xq, const float* __restrict__ xk,
    const float* __restrict__ wq, const float* __restrict__ wk,
    const float* __restrict__ bq, const float* __restrict__ bk,
    unsigned short* __restrict__ q, unsigned short* __restrict__ k) {
    if (blockIdx.z == 0) gemm128_f<false, false, 1024>(xq, wq, bq, q);
    else                 gemm128_f<false, false, 1024>(xk, wk, bk, k);
}

__global__ __launch_bounds__(256) void vt_gemm_f(
    const float* __restrict__ wv, const float* __restrict__ xv,
    const float* __restrict__ bv, unsigned short* __restrict__ VT) {
    gemm128_f<true, true, 4096>(wv, xv, bv, VT);
}

__global__ __launch_bounds__(256) void out_gemm_f(
    const float* __restrict__ wo, const float* __restrict__ bo,
    const unsigned short* __restrict__ ctx, float* __restrict__ out) {
    __shared__ __align__(16) unsigned short Asm[128 * 72];
    __shared__ __align__(16) unsigned short Bsm[128 * 72];
    const int tid = threadIdx.x;
    const int lane = tid & 63;
    const int wv = tid >> 6;
    const int g = lane >> 4;
    const int lm = lane & 15;
    const int wr = wv >> 1;
    const int wc = wv & 1;
    const int m0 = blockIdx.y * 128;
    const int n0 = blockIdx.x * 128;
    floatx4 acc[4][4];
#pragma unroll
    for (int mi = 0; mi < 4; ++mi)
#pragma unroll
        for (int ni = 0; ni < 4; ++ni)
            acc[mi][ni] = (floatx4){0.f, 0.f, 0.f, 0.f};
    for (int k0 = 0; k0 < 1024; k0 += 64) {
#pragma unroll
        for (int i = 0; i < 4; ++i) {
            int idx = tid + i * 256;
            int row = idx >> 3;
            int col = (idx & 7) << 3;
            *(uint4*)&Asm[row * 72 + col] =
                *(const uint4*)&ctx[(size_t)(m0 + row) * 1024 + k0 + col];
            const float* sb = &wo[(size_t)(n0 + row) * 1024 + k0 + col];
            *(short8*)&Bsm[row * 72 + col] = cvt8(*(const float4*)sb, *(const float4*)(sb + 4));
        }
        __syncthreads();
#pragma unroll
        for (int ks = 0; ks < 64; ks += 32) {
            short8 af[4], bfr[4];
#pragma unroll
            for (int mi = 0; mi < 4; ++mi)
                af[mi] = *(const short8*)&Asm[(wr * 64 + mi * 16 + lm) * 72 + ks + g * 8];
#pragma unroll
            for (int ni = 0; ni < 4; ++ni)
                bfr[ni] = *(const short8*)&Bsm[(wc * 64 + ni * 16 + lm) * 72 + ks + g * 8];
#pragma unroll
            for (int mi = 0; mi < 4; ++mi)
#pragma unroll
                for (int ni = 0; ni < 4; ++ni)
                    acc[mi][ni] = __builtin_amdgcn_mfma_f32_16x16x32_bf16(
                        af[mi], bfr[ni], acc[mi][ni], 0, 0, 0);
        }
        __syncthreads();
    }
    float bb[4];
#pragma unroll
    for (int ni = 0; ni < 4; ++ni)
        bb[ni] = bo[n0 + wc * 64 + ni * 16 + lm];
#pragma unroll
    for (int mi = 0; mi < 4; ++mi)
#pragma unroll
        for (int ni = 0; ni < 4; ++ni)
#pragma unroll
            for (int r = 0; r < 4; ++r) {
                int rowg = m0 + wr * 64 + mi * 16 + g * 4 + r;
                int colg = n0 + wc * 64 + ni * 16 + lm;
                out[(size_t)rowg * 1024 + colg] = acc[mi][ni][r] + bb[ni];
            }
}

// ---------------------------------------------------------------------------
// Flash attention (unchanged from r5): KVBLK=128 double-buffered glds staging,
// QBLK=32/wave, exp2 builtin, denominator via ones-MFMA, s_setprio.
// ---------------------------------------------------------------------------
__global__ __launch_bounds__(256) void attn_kernel(
    const unsigned short* __restrict__ Q, const unsigned short* __restrict__ K,
    const unsigned short* __restrict__ VT, unsigned short* __restrict__ CTX) {
    __shared__ __align__(16) unsigned short Ksm[2][128 * 64];   // rows = keys
    __shared__ __align__(16) unsigned short Vtsm[2][128 * 64];  // row = s*64 + feature d

    const int tid = threadIdx.x;
    const int lane = tid & 63;
    const int w = tid >> 6;
    const int g = lane >> 4;
    const int lm = lane & 15;
    const int bh = blockIdx.x;
    const int qt = blockIdx.y;
    const int b = bh >> 4;
    const int h = bh & 15;

    const size_t base = (size_t)b * SEQ * D_MODEL + (size_t)h * DK;
    const size_t vtbase = (size_t)(h * 64) * NTOK + (size_t)b * SEQ;
    const int rs = (lm & 7) << 3;
    const int lr = lane >> 3;
    const int lc = lane & 7;

    union { unsigned u[4]; short8 s; } onev;
    onev.u[0] = 0x3F803F80u; onev.u[1] = 0x3F803F80u;
    onev.u[2] = 0x3F803F80u; onev.u[3] = 0x3F803F80u;

    short8 qf[2][2];
#pragma unroll
    for (int qs = 0; qs < 2; ++qs) {
        const int qrow = qt * 128 + w * 32 + qs * 16 + lm;
#pragma unroll
        for (int t = 0; t < 2; ++t) {
            short8 raw = *(const short8*)&Q[base + (size_t)qrow * D_MODEL + t * 32 + g * 8];
            union { unsigned u[4]; short8 s; } r;
#pragma unroll
            for (int j = 0; j < 4; ++j) {
                float lo = bf2f((unsigned short)raw[2 * j]) * 0.1803368801f;
                float hi = bf2f((unsigned short)raw[2 * j + 1]) * 0.1803368801f;
                r.u[j] = pk2(lo, hi);
            }
            qf[qs][t] = r.s;
        }
    }

    floatx4 Oacc[2][4];
    floatx4 Lacc[2];
#pragma unroll
    for (int qs = 0; qs < 2; ++qs) {
        Lacc[qs] = (floatx4){0.f, 0.f, 0.f, 0.f};
#pragma unroll
        for (int nb = 0; nb < 4; ++nb) Oacc[qs][nb] = (floatx4){0.f, 0.f, 0.f, 0.f};
    }

    auto issue_pair = [&](int pr, int p) {
        const int krow0 = pr * 128;
#pragma unroll
        for (int i = 0; i < 4; ++i) {
            const int r0 = w * 32 + i * 8;
            const int row = r0 + lr;
            const int gcol = (lc ^ (row & 7)) << 3;
            glds16(&K[base + (size_t)(krow0 + row) * D_MODEL + gcol], &Ksm[p][r0 * 64]);
            glds16(&VT[vtbase + (size_t)(row & 63) * NTOK + krow0 + (row >> 6) * 64 + gcol],
                   &Vtsm[p][r0 * 64]);
        }
    };

    const int NP = SEQ / 128;   // 16
    issue_pair(0, 0);
    for (int pr = 0; pr < NP; ++pr) {
        const int p = pr & 1;
        __syncthreads();
        if (pr + 1 < NP) issue_pair(pr + 1, p ^ 1);

#pragma unroll
        for (int s = 0; s < 2; ++s) {
            const unsigned short* Kt = &Ksm[p][s * 4096];
            const unsigned short* Vv = &Vtsm[p][s * 4096];

            float pa[2][4][4];
#pragma unroll
            for (int kb = 0; kb < 4; ++kb) {
                short8 ak0 = *(const short8*)&Kt[(kb * 16 + lm) * 64 + ((0 + g * 8) ^ rs)];
                short8 ak1 = *(const short8*)&Kt[(kb * 16 + lm) * 64 + ((32 + g * 8) ^ rs)];
#pragma unroll
                for (int qs = 0; qs < 2; ++qs) {
                    floatx4 a = (floatx4){0.f, 0.f, 0.f, 0.f};
                    __builtin_amdgcn_s_setprio(1);
                    a = __builtin_amdgcn_mfma_f32_16x16x32_bf16(ak0, qf[qs][0], a, 0, 0, 0);
                    a = __builtin_amdgcn_mfma_f32_16x16x32_bf16(ak1, qf[qs][1], a, 0, 0, 0);
                    __builtin_amdgcn_s_setprio(0);
#pragma unroll
                    for (int r = 0; r < 4; ++r) pa[qs][kb][r] = __builtin_amdgcn_exp2f(a[r]);
                }
            }

#pragma unroll
            for (int cp = 0; cp < 2; ++cp) {
                const int c0 = 2 * cp, c1 = 2 * cp + 1;
                union { unsigned u[4]; short8 s; } ap[2];
#pragma unroll
                for (int qs = 0; qs < 2; ++qs) {
                    ap[qs].u[0] = pk2(pa[qs][c0][0], pa[qs][c0][1]);
                    ap[qs].u[1] = pk2(pa[qs][c0][2], pa[qs][c0][3]);
                    ap[qs].u[2] = pk2(pa[qs][c1][0], pa[qs][c1][1]);
                    ap[qs].u[3] = pk2(pa[qs][c1][2], pa[qs][c1][3]);
                }
                __builtin_amdgcn_s_setprio(1);
#pragma unroll
                for (int nb = 0; nb < 4; ++nb) {
                    const int d = nb * 16 + lm;
                    short8 bv = *(const short8*)&Vv[d * 64 + ((g * 16 + cp * 8) ^ rs)];
                    Oacc[0][nb] = __builtin_amdgcn_mfma_f32_16x16x32_bf16(
                        ap[0].s, bv, Oacc[0][nb], 0, 0, 0);
                    Oacc[1][nb] = __builtin_amdgcn_mfma_f32_16x16x32_bf16(
                        ap[1].s, bv, Oacc[1][nb], 0, 0, 0);
                }
                Lacc[0] = __builtin_amdgcn_mfma_f32_16x16x32_bf16(
                    ap[0].s, onev.s, Lacc[0], 0, 0, 0);
                Lacc[1] = __builtin_amdgcn_mfma_f32_16x16x32_bf16(
                    ap[1].s, onev.s, Lacc[1], 0, 0, 0);
                __builtin_amdgcn_s_setprio(0);
            }
        }
    }

#pragma unroll
    for (int qs = 0; qs < 2; ++qs) {
        float rl[4];
#pragma unroll
        for (int r = 0; r < 4; ++r) rl[r] = 1.0f / Lacc[qs][r];
#pragma unroll
        for (int nb = 0; nb < 4; ++nb) {
#pragma unroll
            for (int r = 0; r < 4; ++r) {
                float val = Oacc[qs][nb][r] * rl[r];
                int srow = qt * 128 + w * 32 + qs * 16 + g * 4 + r;
                CTX[base + (size_t)srow * D_MODEL + nb * 16 + lm] = f2bf(val);
            }
        }
    }
}

extern "C" void kernel_launch(void* const* d_in, const int* in_sizes, int n_in,
                              void* d_out, int out_size, void* d_ws, size_t ws_size,
                              hipStream_t stream) {
    const float* xq = (const float*)d_in[0];
    const float* xk = (const float*)d_in[1];
    const float* xv = (const float*)d_in[2];
    const float* wq = (const float*)d_in[3];
    const float* bq = (const float*)d_in[4];
    const float* wk = (const float*)d_in[5];
    const float* bk = (const float*)d_in[6];
    const float* wv = (const float*)d_in[7];
    const float* bv = (const float*)d_in[8];
    const float* wo = (const float*)d_in[9];
    const float* bo = (const float*)d_in[10];
    float* out = (float*)d_out;

    unsigned short* ws = (unsigned short*)d_ws;

    if (ws_size >= (size_t)68 * 1024 * 1024) {
        // bf16 path: Xb[3*MAT] | Wb[4*WMAT] | Q | K | VT | C
        unsigned short* Xb = ws;
        unsigned short* Wb = ws + (size_t)3 * MAT;
        unsigned short* Qw = Wb + (size_t)4 * WMAT;
        unsigned short* Kw = Qw + (size_t)MAT;
        unsigned short* VTw = Kw + (size_t)MAT;
        unsigned short* Cw = VTw + (size_t)MAT;

        cvt7<<<dim3(2048, 7), 256, 0, stream>>>(xq, xk, xv, wq, wk, wv, wo, ws);
        proj_gemm_b<<<dim3(256, 1, 3), 256, 0, stream>>>(Xb, Wb, bq, bk, bv, Qw, VTw);
        attn_kernel<<<dim3(2 * NH, SEQ / 128), 256, 0, stream>>>(Qw, Kw, VTw, Cw);
        out_gemm_b<<<dim3(8, 64), 256, 0, stream>>>(Cw, Wb + (size_t)3 * WMAT, bo, out);
    } else {
        unsigned short* Qw = ws;
        unsigned short* Kw = ws + (size_t)MAT;
        unsigned short* VTw = ws + (size_t)2 * MAT;
        unsigned short* Cw = ws + (size_t)3 * MAT;
        qkv_gemm_f<<<dim3(8, 32, 2), 256, 0, stream>>>(xq, xk, wq, wk, bq, bk, Qw, Kw);
        vt_gemm_f<<<dim3(32, 8), 256, 0, stream>>>(wv, xv, bv, VTw);
        attn_kernel<<<dim3(2 * NH, SEQ / 128), 256, 0, stream>>>(Qw, Kw, VTw, Cw);
        out_gemm_f<<<dim3(8, 32), 256, 0, stream>>>(wo, bo, Cw, out);
    }
}

// Round 9
// 229.743 us; speedup vs baseline: 1.0004x; 1.0004x over previous
//
#include <hip/hip_runtime.h>
#include <hip/hip_bf16.h>

// MultiheadAttention: B=2, S=2048, D=1024, H=16, dk=64.
// Inputs fp32, output fp32. Internals bf16 MFMA.
// r9 = r7 + NO-DRAIN attention pipeline (T4): two 128-key pairs (16 glds)
// permanently in flight; per pair: s_waitcnt vmcnt(8) -> s_barrier ->
// compute -> s_barrier -> issue pair+2. The vmcnt(0) drain that __syncthreads
// forced once per pair is gone. Last pair peels to vmcnt(0).
// GEMM path unchanged from r7 (single-instantiation merged projections).
// V is produced TRANSPOSED ([feature][token]) with tokens PERMUTED within each
// 64-token tile so the attention PV B-operand is one contiguous b128 LDS read.
// All LDS tiles: stride-64 rows, XOR swizzle col ^= ((row&7)<<3) (16B granule);
// glds staging uses PRE-SWIZZLED GLOBAL SOURCE (linear LDS dest).
// Attention: exp2 builtin (log2e folded into Q prescale), denominator via PV
// MFMA with B=ones, s_setprio(1) around MFMA clusters.

typedef __attribute__((ext_vector_type(8))) short short8;   // 8 bf16 = 4 VGPR (MFMA A/B frag)
typedef __attribute__((ext_vector_type(4))) float floatx4;  // MFMA C/D frag

#define D_MODEL 1024
#define SEQ 2048
#define NTOK 4096      // B*S
#define DK 64
#define NH 16
#define MAT 4194304    // NTOK*D_MODEL
#define WMAT 1048576   // D_MODEL*D_MODEL

static __device__ __forceinline__ unsigned short f2bf(float f) {
    unsigned int x = __float_as_uint(f);
    unsigned int r = x + 0x7fffu + ((x >> 16) & 1u);   // RNE
    return (unsigned short)(r >> 16);
}
static __device__ __forceinline__ float bf2f(unsigned short u) {
    return __uint_as_float(((unsigned int)u) << 16);
}
static __device__ __forceinline__ unsigned pk2(float x, float y) {
    __hip_bfloat162 h = __float22bfloat162_rn(make_float2(x, y));
    return *reinterpret_cast<unsigned*>(&h);
}
static __device__ __forceinline__ short8 cvt8(float4 f0, float4 f1) {
    union { unsigned u[4]; short8 s; } r;
    r.u[0] = pk2(f0.x, f0.y); r.u[1] = pk2(f0.z, f0.w);
    r.u[2] = pk2(f1.x, f1.y); r.u[3] = pk2(f1.z, f1.w);
    return r.s;
}
// token permutation within a 64-token tile: t=c*16+g*4+e -> g*16+c*4+e
static __device__ __forceinline__ int permtok(int t) {
    return ((t >> 2) & 3) * 16 + ((t >> 4) & 3) * 4 + (t & 3);
}
// async global->LDS, 16B per lane; LDS dest = wave-uniform base + lane*16
static __device__ __forceinline__ void glds16(const unsigned short* g, unsigned short* l) {
    __builtin_amdgcn_global_load_lds(
        (const __attribute__((address_space(1))) void*)g,
        (__attribute__((address_space(3))) void*)l, 16, 0, 0);
}

// ---------------------------------------------------------------------------
// fp32 -> bf16 conversion pass: xq,xk,xv (4M each) + wq,wk,wv,wo (1M each)
// ---------------------------------------------------------------------------
__global__ __launch_bounds__(256) void cvt7(
    const float* __restrict__ s0, const float* __restrict__ s1,
    const float* __restrict__ s2, const float* __restrict__ s3,
    const float* __restrict__ s4, const float* __restrict__ s5,
    const float* __restrict__ s6, unsigned short* __restrict__ dst) {
    const float* s; size_t doff; int n;
    switch (blockIdx.y) {
        case 0: s = s0; doff = 0;                          n = MAT;  break;
        case 1: s = s1; doff = (size_t)MAT;                n = MAT;  break;
        case 2: s = s2; doff = (size_t)2 * MAT;            n = MAT;  break;
        case 3: s = s3; doff = (size_t)3 * MAT;            n = WMAT; break;
        case 4: s = s4; doff = (size_t)3 * MAT + WMAT;     n = WMAT; break;
        case 5: s = s5; doff = (size_t)3 * MAT + 2 * WMAT; n = WMAT; break;
        default: s = s6; doff = (size_t)3 * MAT + 3 * WMAT; n = WMAT; break;
    }
    int idx = (blockIdx.x * 256 + threadIdx.x) * 8;
    if (idx >= n) return;
    float4 a = *(const float4*)(s + idx);
    float4 b = *(const float4*)(s + idx + 4);
    *(short8*)&dst[doff + idx] = cvt8(a, b);
}

// ---------------------------------------------------------------------------
// BMx128 NT GEMM, bf16 operands: out[m,n] = sum_k X[m,k]*W[n,k] + bias.
// Template: F32OUT, BM. Runtime: ostride, rowbias, permn (epilogue only) so
// one instantiation serves Q, K and V^T -> one 64 KB LDS allocation.
// Double-buffered LDS, glds16 staging (pre-swizzled source), one
// __syncthreads per k-step with prefetch issued post-barrier.
// ---------------------------------------------------------------------------
template <bool F32OUT, int BM>
static __device__ __forceinline__ void gemm_bb(const unsigned short* __restrict__ X,
                                               const unsigned short* __restrict__ W,
                                               const float* __restrict__ bias,
                                               void* __restrict__ outp,
                                               int m0, int n0,
                                               int ostride, bool rowbias, bool permn) {
    __shared__ __align__(16) unsigned short Asm[2][BM * 64];
    __shared__ __align__(16) unsigned short Bsm[2][128 * 64];
    constexpr int MF = BM / 32;          // m-fragments per wave
    constexpr int HALF = BM / 2;

    const int tid = threadIdx.x;
    const int lane = tid & 63;
    const int wv = tid >> 6;
    const int g = lane >> 4;
    const int lm = lane & 15;
    const int wr = wv >> 1;
    const int wc = wv & 1;
    const int rs = (lm & 7) << 3;          // read-side swizzle
    const int lr = lane >> 3;              // 0..7 : row within a glds group
    const int lc = lane & 7;               // 16B slot within row

    auto issue = [&](int k0, int p) {
#pragma unroll
        for (int i = 0; i < BM / 32; ++i) {
            const int r0 = wv * (BM / 4) + i * 8;
            const int row = r0 + lr;
            const int gcol = (lc ^ (row & 7)) << 3;
            glds16(&X[(size_t)(m0 + row) * 1024 + k0 + gcol], &Asm[p][r0 * 64]);
        }
#pragma unroll
        for (int i = 0; i < 4; ++i) {
            const int r0 = wv * 32 + i * 8;
            const int row = r0 + lr;
            const int gcol = (lc ^ (row & 7)) << 3;
            glds16(&W[(size_t)(n0 + row) * 1024 + k0 + gcol], &Bsm[p][r0 * 64]);
        }
    };

    floatx4 acc[MF][4];
#pragma unroll
    for (int mi = 0; mi < MF; ++mi)
#pragma unroll
        for (int ni = 0; ni < 4; ++ni)
            acc[mi][ni] = (floatx4){0.f, 0.f, 0.f, 0.f};

    issue(0, 0);
    for (int k0 = 0, it = 0; k0 < 1024; k0 += 64, ++it) {
        const int p = it & 1;
        __syncthreads();                         // vmcnt drain: tile it in LDS, all waves
        if (k0 + 64 < 1024) issue(k0 + 64, p ^ 1);   // prefetch lands during compute
#pragma unroll
        for (int ks = 0; ks < 64; ks += 32) {
            short8 af[MF], bfr[4];
#pragma unroll
            for (int mi = 0; mi < MF; ++mi)
                af[mi] = *(const short8*)&Asm[p][(wr * HALF + mi * 16 + lm) * 64 +
                                                ((ks + g * 8) ^ rs)];
#pragma unroll
            for (int ni = 0; ni < 4; ++ni)
                bfr[ni] = *(const short8*)&Bsm[p][(wc * 64 + ni * 16 + lm) * 64 +
                                                 ((ks + g * 8) ^ rs)];
#pragma unroll
            for (int mi = 0; mi < MF; ++mi)
#pragma unroll
                for (int ni = 0; ni < 4; ++ni)
                    acc[mi][ni] = __builtin_amdgcn_mfma_f32_16x16x32_bf16(
                        af[mi], bfr[ni], acc[mi][ni], 0, 0, 0);
        }
    }

    float cb[4];
#pragma unroll
    for (int ni = 0; ni < 4; ++ni)
        cb[ni] = rowbias ? 0.f : bias[n0 + wc * 64 + ni * 16 + lm];
#pragma unroll
    for (int mi = 0; mi < MF; ++mi)
#pragma unroll
        for (int r = 0; r < 4; ++r) {
            int rowg = m0 + wr * HALF + mi * 16 + g * 4 + r;
            float rb = rowbias ? bias[rowg] : 0.f;
#pragma unroll
            for (int ni = 0; ni < 4; ++ni) {
                int colg = n0 + wc * 64 + ni * 16 + lm;
                if (permn) colg = (colg & ~63) | permtok(colg & 63);
                float val = acc[mi][ni][r] + (rowbias ? rb : cb[ni]);
                if (F32OUT)
                    ((float*)outp)[(size_t)rowg * ostride + colg] = val;
                else
                    ((unsigned short*)outp)[(size_t)rowg * ostride + colg] = f2bf(val);
            }
        }
}

// Merged projections (one instantiation, runtime flags):
//   z=0: Q  = Xq @ Wq^T + bq          (m=tokens, n=features)
//   z=1: K  = Xk @ Wk^T + bk
//   z=2: VT = (Wv @ Xv^T)^perm + bv   (m=features, n=tokens, rowbias+permn)
__global__ __launch_bounds__(256) void proj_gemm_b(
    const unsigned short* __restrict__ Xb, const unsigned short* __restrict__ Wb,
    const float* __restrict__ bq, const float* __restrict__ bk,
    const float* __restrict__ bv, unsigned short* __restrict__ QK,
    unsigned short* __restrict__ VT) {
    const int z = blockIdx.z;
    const int bid = blockIdx.x;            // 0..255
    if (z == 0)
        gemm_bb<false, 128>(Xb, Wb, bq, QK,
                            (bid >> 3) * 128, (bid & 7) * 128, 1024, false, false);
    else if (z == 1)
        gemm_bb<false, 128>(Xb + (size_t)MAT, Wb + (size_t)WMAT, bk,
                            QK + (size_t)MAT,
                            (bid >> 3) * 128, (bid & 7) * 128, 1024, false, false);
    else
        gemm_bb<false, 128>(Wb + (size_t)2 * WMAT, Xb + (size_t)2 * MAT, bv, VT,
                            (bid & 7) * 128, (bid >> 3) * 128, 4096, true, true);
}

__global__ __launch_bounds__(256) void out_gemm_b(
    const unsigned short* __restrict__ ctx, const unsigned short* __restrict__ Wo,
    const float* __restrict__ bo, float* __restrict__ out) {
    gemm_bb<true, 64>(ctx, Wo, bo, out, blockIdx.y * 64, blockIdx.x * 128,
                      1024, false, false);
}

// ---------------- fallback path (fp32 staging), used if ws too small --------
template <bool ROWBIAS, bool PERMN, int OSTRIDE>
static __device__ __forceinline__ void gemm128_f(const float* __restrict__ X,
                                                 const float* __restrict__ W,
                                                 const float* __restrict__ bias,
                                                 unsigned short* __restrict__ out) {
    __shared__ __align__(16) unsigned short Asm[128 * 72];
    __shared__ __align__(16) unsigned short Bsm[128 * 72];
    const int tid = threadIdx.x;
    const int lane = tid & 63;
    const int wv = tid >> 6;
    const int g = lane >> 4;
    const int lm = lane & 15;
    const int wr = wv >> 1;
    const int wc = wv & 1;
    const int m0 = blockIdx.y * 128;
    const int n0 = blockIdx.x * 128;
    floatx4 acc[4][4];
#pragma unroll
    for (int mi = 0; mi < 4; ++mi)
#pragma unroll
        for (int ni = 0; ni < 4; ++ni)
            acc[mi][ni] = (floatx4){0.f, 0.f, 0.f, 0.f};
    for (int k0 = 0; k0 < 1024; k0 += 64) {
#pragma unroll
        for (int i = 0; i < 4; ++i) {
            int idx = tid + i * 256;
            int row = idx >> 3;
            int col = (idx & 7) << 3;
            const float* sa = &X[(size_t)(m0 + row) * 1024 + k0 + col];
            *(short8*)&Asm[row * 72 + col] = cvt8(*(const float4*)sa, *(const float4*)(sa + 4));
            const float* sb = &W[(size_t)(n0 + row) * 1024 + k0 + col];
            *(short8*)&Bsm[row * 72 + col] = cvt8(*(const float4*)sb, *(const float4*)(sb + 4));
        }
        __syncthreads();
#pragma unroll
        for (int ks = 0; ks < 64; ks += 32) {
            short8 af[4], bfr[4];
#pragma unroll
            for (int mi = 0; mi < 4; ++mi)
                af[mi] = *(const short8*)&Asm[(wr * 64 + mi * 16 + lm) * 72 + ks + g * 8];
#pragma unroll
            for (int ni = 0; ni < 4; ++ni)
                bfr[ni] = *(const short8*)&Bsm[(wc * 64 + ni * 16 + lm) * 72 + ks + g * 8];
#pragma unroll
            for (int mi = 0; mi < 4; ++mi)
#pragma unroll
                for (int ni = 0; ni < 4; ++ni)
                    acc[mi][ni] = __builtin_amdgcn_mfma_f32_16x16x32_bf16(
                        af[mi], bfr[ni], acc[mi][ni], 0, 0, 0);
        }
        __syncthreads();
    }
    float cb[4];
#pragma unroll
    for (int ni = 0; ni < 4; ++ni)
        cb[ni] = ROWBIAS ? 0.f : bias[n0 + wc * 64 + ni * 16 + lm];
#pragma unroll
    for (int mi = 0; mi < 4; ++mi)
#pragma unroll
        for (int r = 0; r < 4; ++r) {
            int rowg = m0 + wr * 64 + mi * 16 + g * 4 + r;
            float rb = ROWBIAS ? bias[rowg] : 0.f;
#pragma unroll
            for (int ni = 0; ni < 4; ++ni) {
                int colg = n0 + wc * 64 + ni * 16 + lm;
                if (PERMN) colg = (colg & ~63) | permtok(colg & 63);
                out[(size_t)rowg * OSTRIDE + colg] =
                    f2bf(acc[mi][ni][r] + (ROWBIAS ? rb : cb[ni]));
            }
        }
}

__global__ __launch_bounds__(256) void qkv_gemm_f(
    const float* __restrict__ xq, const float* __restrict__ xk,
    const float* __restrict__ wq, const float* __restrict__ wk,
    const float* __restrict__ bq, const float* __restrict__ bk,
    unsigned short* __restrict__ q, unsigned short* __restrict__ k) {
    if (blockIdx.z == 0) gemm128_f<false, false, 1024>(xq, wq, bq, q);
    else                 gemm128_f<false, false, 1024>(xk, wk, bk, k);
}

__global__ __launch_bounds__(256) void vt_gemm_f(
    const float* __restrict__ wv, const float* __restrict__ xv,
    const float* __restrict__ bv, unsigned short* __restrict__ VT) {
    gemm128_f<true, true, 4096>(wv, xv, bv, VT);
}

__global__ __launch_bounds__(256) void out_gemm_f(
    const float* __restrict__ wo, const float* __restrict__ bo,
    const unsigned short* __restrict__ ctx, float* __restrict__ out) {
    __shared__ __align__(16) unsigned short Asm[128 * 72];
    __shared__ __align__(16) unsigned short Bsm[128 * 72];
    const int tid = threadIdx.x;
    const int lane = tid & 63;
    const int wv = tid >> 6;
    const int g = lane >> 4;
    const int lm = lane & 15;
    const int wr = wv >> 1;
    const int wc = wv & 1;
    const int m0 = blockIdx.y * 128;
    const int n0 = blockIdx.x * 128;
    floatx4 acc[4][4];
#pragma unroll
    for (int mi = 0; mi < 4; ++mi)
#pragma unroll
        for (int ni = 0; ni < 4; ++ni)
            acc[mi][ni] = (floatx4){0.f, 0.f, 0.f, 0.f};
    for (int k0 = 0; k0 < 1024; k0 += 64) {
#pragma unroll
        for (int i = 0; i < 4; ++i) {
            int idx = tid + i * 256;
            int row = idx >> 3;
            int col = (idx & 7) << 3;
            *(uint4*)&Asm[row * 72 + col] =
                *(const uint4*)&ctx[(size_t)(m0 + row) * 1024 + k0 + col];
            const float* sb = &wo[(size_t)(n0 + row) * 1024 + k0 + col];
            *(short8*)&Bsm[row * 72 + col] = cvt8(*(const float4*)sb, *(const float4*)(sb + 4));
        }
        __syncthreads();
#pragma unroll
        for (int ks = 0; ks < 64; ks += 32) {
            short8 af[4], bfr[4];
#pragma unroll
            for (int mi = 0; mi < 4; ++mi)
                af[mi] = *(const short8*)&Asm[(wr * 64 + mi * 16 + lm) * 72 + ks + g * 8];
#pragma unroll
            for (int ni = 0; ni < 4; ++ni)
                bfr[ni] = *(const short8*)&Bsm[(wc * 64 + ni * 16 + lm) * 72 + ks + g * 8];
#pragma unroll
            for (int mi = 0; mi < 4; ++mi)
#pragma unroll
                for (int ni = 0; ni < 4; ++ni)
                    acc[mi][ni] = __builtin_amdgcn_mfma_f32_16x16x32_bf16(
                        af[mi], bfr[ni], acc[mi][ni], 0, 0, 0);
        }
        __syncthreads();
    }
    float bb[4];
#pragma unroll
    for (int ni = 0; ni < 4; ++ni)
        bb[ni] = bo[n0 + wc * 64 + ni * 16 + lm];
#pragma unroll
    for (int mi = 0; mi < 4; ++mi)
#pragma unroll
        for (int ni = 0; ni < 4; ++ni)
#pragma unroll
            for (int r = 0; r < 4; ++r) {
                int rowg = m0 + wr * 64 + mi * 16 + g * 4 + r;
                int colg = n0 + wc * 64 + ni * 16 + lm;
                out[(size_t)rowg * 1024 + colg] = acc[mi][ni][r] + bb[ni];
            }
}

// ---------------------------------------------------------------------------
// Flash attention r9: no-drain pipeline. Two 128-key pairs (16 glds) always
// in flight. Per pair: vmcnt(8) [my pr loads done, FIFO] -> s_barrier [all
// waves' pr loads done + all done reading buf[pr-2]] -> compute ->
// s_barrier [all done reading buf[pr&1]] -> issue pair pr+2 into buf[pr&1].
// Last pair: vmcnt(0). QBLK=32/wave, exp2 builtin, ones-MFMA denominator,
// s_setprio around MFMA clusters.
// ---------------------------------------------------------------------------
__global__ __launch_bounds__(256) void attn_kernel(
    const unsigned short* __restrict__ Q, const unsigned short* __restrict__ K,
    const unsigned short* __restrict__ VT, unsigned short* __restrict__ CTX) {
    __shared__ __align__(16) unsigned short Ksm[2][128 * 64];   // rows = keys
    __shared__ __align__(16) unsigned short Vtsm[2][128 * 64];  // row = s*64 + feature d

    const int tid = threadIdx.x;
    const int lane = tid & 63;
    const int w = tid >> 6;
    const int g = lane >> 4;
    const int lm = lane & 15;
    const int bh = blockIdx.x;
    const int qt = blockIdx.y;
    const int b = bh >> 4;
    const int h = bh & 15;

    const size_t base = (size_t)b * SEQ * D_MODEL + (size_t)h * DK;
    const size_t vtbase = (size_t)(h * 64) * NTOK + (size_t)b * SEQ;
    const int rs = (lm & 7) << 3;
    const int lr = lane >> 3;
    const int lc = lane & 7;

    union { unsigned u[4]; short8 s; } onev;
    onev.u[0] = 0x3F803F80u; onev.u[1] = 0x3F803F80u;
    onev.u[2] = 0x3F803F80u; onev.u[3] = 0x3F803F80u;

    short8 qf[2][2];
#pragma unroll
    for (int qs = 0; qs < 2; ++qs) {
        const int qrow = qt * 128 + w * 32 + qs * 16 + lm;
#pragma unroll
        for (int t = 0; t < 2; ++t) {
            short8 raw = *(const short8*)&Q[base + (size_t)qrow * D_MODEL + t * 32 + g * 8];
            union { unsigned u[4]; short8 s; } r;
#pragma unroll
            for (int j = 0; j < 4; ++j) {
                float lo = bf2f((unsigned short)raw[2 * j]) * 0.1803368801f;
                float hi = bf2f((unsigned short)raw[2 * j + 1]) * 0.1803368801f;
                r.u[j] = pk2(lo, hi);
            }
            qf[qs][t] = r.s;
        }
    }

    floatx4 Oacc[2][4];
    floatx4 Lacc[2];
#pragma unroll
    for (int qs = 0; qs < 2; ++qs) {
        Lacc[qs] = (floatx4){0.f, 0.f, 0.f, 0.f};
#pragma unroll
        for (int nb = 0; nb < 4; ++nb) Oacc[qs][nb] = (floatx4){0.f, 0.f, 0.f, 0.f};
    }

    // 8 glds per wave per pair: wave w fills LDS rows [w*32, w*32+32)
    auto issue_pair = [&](int pr, int p) {
        const int krow0 = pr * 128;
#pragma unroll
        for (int i = 0; i < 4; ++i) {
            const int r0 = w * 32 + i * 8;
            const int row = r0 + lr;
            const int gcol = (lc ^ (row & 7)) << 3;
            glds16(&K[base + (size_t)(krow0 + row) * D_MODEL + gcol], &Ksm[p][r0 * 64]);
            glds16(&VT[vtbase + (size_t)(row & 63) * NTOK + krow0 + (row >> 6) * 64 + gcol],
                   &Vtsm[p][r0 * 64]);
        }
    };

    const int NP = SEQ / 128;   // 16
    issue_pair(0, 0);           // vm = 8
    issue_pair(1, 1);           // vm = 16
    for (int pr = 0; pr < NP; ++pr) {
        const int p = pr & 1;
        // my pair-pr loads complete (oldest 8 of <=16 outstanding). FIFO vmcnt.
        if (pr + 1 < NP) asm volatile("s_waitcnt vmcnt(8)" ::: "memory");
        else             asm volatile("s_waitcnt vmcnt(0)" ::: "memory");
        // barrier aggregates: every wave has waited its own vmcnt -> pair pr
        // fully in LDS; also orders vs. previous iteration's buffer overwrite.
        __builtin_amdgcn_s_barrier();

#pragma unroll
        for (int s = 0; s < 2; ++s) {
            const unsigned short* Kt = &Ksm[p][s * 4096];
            const unsigned short* Vv = &Vtsm[p][s * 4096];

            float pa[2][4][4];
#pragma unroll
            for (int kb = 0; kb < 4; ++kb) {
                short8 ak0 = *(const short8*)&Kt[(kb * 16 + lm) * 64 + ((0 + g * 8) ^ rs)];
                short8 ak1 = *(const short8*)&Kt[(kb * 16 + lm) * 64 + ((32 + g * 8) ^ rs)];
#pragma unroll
                for (int qs = 0; qs < 2; ++qs) {
                    floatx4 a = (floatx4){0.f, 0.f, 0.f, 0.f};
                    __builtin_amdgcn_s_setprio(1);
                    a = __builtin_amdgcn_mfma_f32_16x16x32_bf16(ak0, qf[qs][0], a, 0, 0, 0);
                    a = __builtin_amdgcn_mfma_f32_16x16x32_bf16(ak1, qf[qs][1], a, 0, 0, 0);
                    __builtin_amdgcn_s_setprio(0);
#pragma unroll
                    for (int r = 0; r < 4; ++r) pa[qs][kb][r] = __builtin_amdgcn_exp2f(a[r]);
                }
            }

#pragma unroll
            for (int cp = 0; cp < 2; ++cp) {
                const int c0 = 2 * cp, c1 = 2 * cp + 1;
                union { unsigned u[4]; short8 s; } ap[2];
#pragma unroll
                for (int qs = 0; qs < 2; ++qs) {
                    ap[qs].u[0] = pk2(pa[qs][c0][0], pa[qs][c0][1]);
                    ap[qs].u[1] = pk2(pa[qs][c0][2], pa[qs][c0][3]);
                    ap[qs].u[2] = pk2(pa[qs][c1][0], pa[qs][c1][1]);
                    ap[qs].u[3] = pk2(pa[qs][c1][2], pa[qs][c1][3]);
                }
                __builtin_amdgcn_s_setprio(1);
#pragma unroll
                for (int nb = 0; nb < 4; ++nb) {
                    const int d = nb * 16 + lm;
                    short8 bv = *(const short8*)&Vv[d * 64 + ((g * 16 + cp * 8) ^ rs)];
                    Oacc[0][nb] = __builtin_amdgcn_mfma_f32_16x16x32_bf16(
                        ap[0].s, bv, Oacc[0][nb], 0, 0, 0);
                    Oacc[1][nb] = __builtin_amdgcn_mfma_f32_16x16x32_bf16(
                        ap[1].s, bv, Oacc[1][nb], 0, 0, 0);
                }
                Lacc[0] = __builtin_amdgcn_mfma_f32_16x16x32_bf16(
                    ap[0].s, onev.s, Lacc[0], 0, 0, 0);
                Lacc[1] = __builtin_amdgcn_mfma_f32_16x16x32_bf16(
                    ap[1].s, onev.s, Lacc[1], 0, 0, 0);
                __builtin_amdgcn_s_setprio(0);
            }
        }

        // all waves done reading buf[p] -> safe to overwrite with pair pr+2.
        __builtin_amdgcn_s_barrier();
        if (pr + 2 < NP) issue_pair(pr + 2, p);
    }

#pragma unroll
    for (int qs = 0; qs < 2; ++qs) {
        float rl[4];
#pragma unroll
        for (int r = 0; r < 4; ++r) rl[r] = 1.0f / Lacc[qs][r];
#pragma unroll
        for (int nb = 0; nb < 4; ++nb) {
#pragma unroll
            for (int r = 0; r < 4; ++r) {
                float val = Oacc[qs][nb][r] * rl[r];
                int srow = qt * 128 + w * 32 + qs * 16 + g * 4 + r;
                CTX[base + (size_t)srow * D_MODEL + nb * 16 + lm] = f2bf(val);
            }
        }
    }
}

extern "C" void kernel_launch(void* const* d_in, const int* in_sizes, int n_in,
                              void* d_out, int out_size, void* d_ws, size_t ws_size,
                              hipStream_t stream) {
    const float* xq = (const float*)d_in[0];
    const float* xk = (const float*)d_in[1];
    const float* xv = (const float*)d_in[2];
    const float* wq = (const float*)d_in[3];
    const float* bq = (const float*)d_in[4];
    const float* wk = (const float*)d_in[5];
    const float* bk = (const float*)d_in[6];
    const float* wv = (const float*)d_in[7];
    const float* bv = (const float*)d_in[8];
    const float* wo = (const float*)d_in[9];
    const float* bo = (const float*)d_in[10];
    float* out = (float*)d_out;

    unsigned short* ws = (unsigned short*)d_ws;

    if (ws_size >= (size_t)68 * 1024 * 1024) {
        // bf16 path: Xb[3*MAT] | Wb[4*WMAT] | Q | K | VT | C
        unsigned short* Xb = ws;
        unsigned short* Wb = ws + (size_t)3 * MAT;
        unsigned short* Qw = Wb + (size_t)4 * WMAT;
        unsigned short* Kw = Qw + (size_t)MAT;
        unsigned short* VTw = Kw + (size_t)MAT;
        unsigned short* Cw = VTw + (size_t)MAT;

        cvt7<<<dim3(2048, 7), 256, 0, stream>>>(xq, xk, xv, wq, wk, wv, wo, ws);
        proj_gemm_b<<<dim3(256, 1, 3), 256, 0, stream>>>(Xb, Wb, bq, bk, bv, Qw, VTw);
        attn_kernel<<<dim3(2 * NH, SEQ / 128), 256, 0, stream>>>(Qw, Kw, VTw, Cw);
        out_gemm_b<<<dim3(8, 64), 256, 0, stream>>>(Cw, Wb + (size_t)3 * WMAT, bo, out);
    } else {
        unsigned short* Qw = ws;
        unsigned short* Kw = ws + (size_t)MAT;
        unsigned short* VTw = ws + (size_t)2 * MAT;
        unsigned short* Cw = ws + (size_t)3 * MAT;
        qkv_gemm_f<<<dim3(8, 32, 2), 256, 0, stream>>>(xq, xk, wq, wk, bq, bk, Qw, Kw);
        vt_gemm_f<<<dim3(32, 8), 256, 0, stream>>>(wv, xv, bv, VTw);
        attn_kernel<<<dim3(2 * NH, SEQ / 128), 256, 0, stream>>>(Qw, Kw, VTw, Cw);
        out_gemm_f<<<dim3(8, 32), 256, 0, stream>>>(wo, bo, Cw, out);
    }
}

// Round 10
// 224.850 us; speedup vs baseline: 1.0222x; 1.0218x over previous
//
#include <hip/hip_runtime.h>
#include <hip/hip_bf16.h>

// MultiheadAttention: B=2, S=2048, D=1024, H=16, dk=64.
// Inputs fp32, output fp32. Internals bf16 MFMA.
// r10 = r9 attn (no-drain pipeline, proven) + GEMMs reverted to the m97
// SINGLE-BUFFER 32 KB structure: issue(k)->sync->compute(k)->sync->issue(k+1).
// Rationale: all prior rounds used 64 KB dbuf -> 2 blocks/CU; proj's 768-block
// grid ran 512 + half-empty 256 tail. At 32 KB all 768 co-resident (3/CU,
// 12 waves/CU), tail gone; m99/m100 show explicit dbuf adds nothing over
// implicit multi-block overlap.
// V is produced TRANSPOSED ([feature][token]) with tokens PERMUTED within each
// 64-token tile so the attention PV B-operand is one contiguous b128 LDS read.
// All LDS tiles: stride-64 rows, XOR swizzle col ^= ((row&7)<<3) (16B granule);
// glds staging uses PRE-SWIZZLED GLOBAL SOURCE (linear LDS dest).
// Attention: exp2 builtin (log2e folded into Q prescale), denominator via PV
// MFMA with B=ones, s_setprio(1) around MFMA clusters.

typedef __attribute__((ext_vector_type(8))) short short8;   // 8 bf16 = 4 VGPR (MFMA A/B frag)
typedef __attribute__((ext_vector_type(4))) float floatx4;  // MFMA C/D frag

#define D_MODEL 1024
#define SEQ 2048
#define NTOK 4096      // B*S
#define DK 64
#define NH 16
#define MAT 4194304    // NTOK*D_MODEL
#define WMAT 1048576   // D_MODEL*D_MODEL

static __device__ __forceinline__ unsigned short f2bf(float f) {
    unsigned int x = __float_as_uint(f);
    unsigned int r = x + 0x7fffu + ((x >> 16) & 1u);   // RNE
    return (unsigned short)(r >> 16);
}
static __device__ __forceinline__ float bf2f(unsigned short u) {
    return __uint_as_float(((unsigned int)u) << 16);
}
static __device__ __forceinline__ unsigned pk2(float x, float y) {
    __hip_bfloat162 h = __float22bfloat162_rn(make_float2(x, y));
    return *reinterpret_cast<unsigned*>(&h);
}
static __device__ __forceinline__ short8 cvt8(float4 f0, float4 f1) {
    union { unsigned u[4]; short8 s; } r;
    r.u[0] = pk2(f0.x, f0.y); r.u[1] = pk2(f0.z, f0.w);
    r.u[2] = pk2(f1.x, f1.y); r.u[3] = pk2(f1.z, f1.w);
    return r.s;
}
// token permutation within a 64-token tile: t=c*16+g*4+e -> g*16+c*4+e
static __device__ __forceinline__ int permtok(int t) {
    return ((t >> 2) & 3) * 16 + ((t >> 4) & 3) * 4 + (t & 3);
}
// async global->LDS, 16B per lane; LDS dest = wave-uniform base + lane*16
static __device__ __forceinline__ void glds16(const unsigned short* g, unsigned short* l) {
    __builtin_amdgcn_global_load_lds(
        (const __attribute__((address_space(1))) void*)g,
        (__attribute__((address_space(3))) void*)l, 16, 0, 0);
}

// ---------------------------------------------------------------------------
// fp32 -> bf16 conversion pass: xq,xk,xv (4M each) + wq,wk,wv,wo (1M each)
// ---------------------------------------------------------------------------
__global__ __launch_bounds__(256) void cvt7(
    const float* __restrict__ s0, const float* __restrict__ s1,
    const float* __restrict__ s2, const float* __restrict__ s3,
    const float* __restrict__ s4, const float* __restrict__ s5,
    const float* __restrict__ s6, unsigned short* __restrict__ dst) {
    const float* s; size_t doff; int n;
    switch (blockIdx.y) {
        case 0: s = s0; doff = 0;                          n = MAT;  break;
        case 1: s = s1; doff = (size_t)MAT;                n = MAT;  break;
        case 2: s = s2; doff = (size_t)2 * MAT;            n = MAT;  break;
        case 3: s = s3; doff = (size_t)3 * MAT;            n = WMAT; break;
        case 4: s = s4; doff = (size_t)3 * MAT + WMAT;     n = WMAT; break;
        case 5: s = s5; doff = (size_t)3 * MAT + 2 * WMAT; n = WMAT; break;
        default: s = s6; doff = (size_t)3 * MAT + 3 * WMAT; n = WMAT; break;
    }
    int idx = (blockIdx.x * 256 + threadIdx.x) * 8;
    if (idx >= n) return;
    float4 a = *(const float4*)(s + idx);
    float4 b = *(const float4*)(s + idx + 4);
    *(short8*)&dst[doff + idx] = cvt8(a, b);
}

// ---------------------------------------------------------------------------
// BMx128 NT GEMM, bf16 operands: out[m,n] = sum_k X[m,k]*W[n,k] + bias.
// m97 single-buffer structure (32 KB for BM=128): issue(k) -> sync (drains
// glds vmcnt) -> compute(k) -> sync (all reads done) -> issue(k+1).
// Template: F32OUT, BM. Runtime: ostride, rowbias, permn (epilogue only) so
// one instantiation serves Q, K and V^T.
// ---------------------------------------------------------------------------
template <bool F32OUT, int BM>
static __device__ __forceinline__ void gemm_bb(const unsigned short* __restrict__ X,
                                               const unsigned short* __restrict__ W,
                                               const float* __restrict__ bias,
                                               void* __restrict__ outp,
                                               int m0, int n0,
                                               int ostride, bool rowbias, bool permn) {
    __shared__ __align__(16) unsigned short Asm[BM * 64];
    __shared__ __align__(16) unsigned short Bsm[128 * 64];
    constexpr int MF = BM / 32;          // m-fragments per wave
    constexpr int HALF = BM / 2;

    const int tid = threadIdx.x;
    const int lane = tid & 63;
    const int wv = tid >> 6;
    const int g = lane >> 4;
    const int lm = lane & 15;
    const int wr = wv >> 1;
    const int wc = wv & 1;
    const int rs = (lm & 7) << 3;          // read-side swizzle
    const int lr = lane >> 3;              // 0..7 : row within a glds group
    const int lc = lane & 7;               // 16B slot within row

    auto issue = [&](int k0) {
#pragma unroll
        for (int i = 0; i < BM / 32; ++i) {
            const int r0 = wv * (BM / 4) + i * 8;
            const int row = r0 + lr;
            const int gcol = (lc ^ (row & 7)) << 3;
            glds16(&X[(size_t)(m0 + row) * 1024 + k0 + gcol], &Asm[r0 * 64]);
        }
#pragma unroll
        for (int i = 0; i < 4; ++i) {
            const int r0 = wv * 32 + i * 8;
            const int row = r0 + lr;
            const int gcol = (lc ^ (row & 7)) << 3;
            glds16(&W[(size_t)(n0 + row) * 1024 + k0 + gcol], &Bsm[r0 * 64]);
        }
    };

    floatx4 acc[MF][4];
#pragma unroll
    for (int mi = 0; mi < MF; ++mi)
#pragma unroll
        for (int ni = 0; ni < 4; ++ni)
            acc[mi][ni] = (floatx4){0.f, 0.f, 0.f, 0.f};

    issue(0);
    for (int k0 = 0; k0 < 1024; k0 += 64) {
        __syncthreads();                   // glds(k0) drained & visible to all
#pragma unroll
        for (int ks = 0; ks < 64; ks += 32) {
            short8 af[MF], bfr[4];
#pragma unroll
            for (int mi = 0; mi < MF; ++mi)
                af[mi] = *(const short8*)&Asm[(wr * HALF + mi * 16 + lm) * 64 +
                                              ((ks + g * 8) ^ rs)];
#pragma unroll
            for (int ni = 0; ni < 4; ++ni)
                bfr[ni] = *(const short8*)&Bsm[(wc * 64 + ni * 16 + lm) * 64 +
                                               ((ks + g * 8) ^ rs)];
#pragma unroll
            for (int mi = 0; mi < MF; ++mi)
#pragma unroll
                for (int ni = 0; ni < 4; ++ni)
                    acc[mi][ni] = __builtin_amdgcn_mfma_f32_16x16x32_bf16(
                        af[mi], bfr[ni], acc[mi][ni], 0, 0, 0);
        }
        __syncthreads();                   // all waves done reading the buffer
        if (k0 + 64 < 1024) issue(k0 + 64);
    }

    float cb[4];
#pragma unroll
    for (int ni = 0; ni < 4; ++ni)
        cb[ni] = rowbias ? 0.f : bias[n0 + wc * 64 + ni * 16 + lm];
#pragma unroll
    for (int mi = 0; mi < MF; ++mi)
#pragma unroll
        for (int r = 0; r < 4; ++r) {
            int rowg = m0 + wr * HALF + mi * 16 + g * 4 + r;
            float rb = rowbias ? bias[rowg] : 0.f;
#pragma unroll
            for (int ni = 0; ni < 4; ++ni) {
                int colg = n0 + wc * 64 + ni * 16 + lm;
                if (permn) colg = (colg & ~63) | permtok(colg & 63);
                float val = acc[mi][ni][r] + (rowbias ? rb : cb[ni]);
                if (F32OUT)
                    ((float*)outp)[(size_t)rowg * ostride + colg] = val;
                else
                    ((unsigned short*)outp)[(size_t)rowg * ostride + colg] = f2bf(val);
            }
        }
}

// Merged projections (one instantiation, runtime flags):
//   z=0: Q  = Xq @ Wq^T + bq          (m=tokens, n=features)
//   z=1: K  = Xk @ Wk^T + bk
//   z=2: VT = (Wv @ Xv^T)^perm + bv   (m=features, n=tokens, rowbias+permn)
__global__ __launch_bounds__(256) void proj_gemm_b(
    const unsigned short* __restrict__ Xb, const unsigned short* __restrict__ Wb,
    const float* __restrict__ bq, const float* __restrict__ bk,
    const float* __restrict__ bv, unsigned short* __restrict__ QK,
    unsigned short* __restrict__ VT) {
    const int z = blockIdx.z;
    const int bid = blockIdx.x;            // 0..255
    if (z == 0)
        gemm_bb<false, 128>(Xb, Wb, bq, QK,
                            (bid >> 3) * 128, (bid & 7) * 128, 1024, false, false);
    else if (z == 1)
        gemm_bb<false, 128>(Xb + (size_t)MAT, Wb + (size_t)WMAT, bk,
                            QK + (size_t)MAT,
                            (bid >> 3) * 128, (bid & 7) * 128, 1024, false, false);
    else
        gemm_bb<false, 128>(Wb + (size_t)2 * WMAT, Xb + (size_t)2 * MAT, bv, VT,
                            (bid & 7) * 128, (bid >> 3) * 128, 4096, true, true);
}

__global__ __launch_bounds__(256) void out_gemm_b(
    const unsigned short* __restrict__ ctx, const unsigned short* __restrict__ Wo,
    const float* __restrict__ bo, float* __restrict__ out) {
    gemm_bb<true, 64>(ctx, Wo, bo, out, blockIdx.y * 64, blockIdx.x * 128,
                      1024, false, false);
}

// ---------------- fallback path (fp32 staging), used if ws too small --------
template <bool ROWBIAS, bool PERMN, int OSTRIDE>
static __device__ __forceinline__ void gemm128_f(const float* __restrict__ X,
                                                 const float* __restrict__ W,
                                                 const float* __restrict__ bias,
                                                 unsigned short* __restrict__ out) {
    __shared__ __align__(16) unsigned short Asm[128 * 72];
    __shared__ __align__(16) unsigned short Bsm[128 * 72];
    const int tid = threadIdx.x;
    const int lane = tid & 63;
    const int wv = tid >> 6;
    const int g = lane >> 4;
    const int lm = lane & 15;
    const int wr = wv >> 1;
    const int wc = wv & 1;
    const int m0 = blockIdx.y * 128;
    const int n0 = blockIdx.x * 128;
    floatx4 acc[4][4];
#pragma unroll
    for (int mi = 0; mi < 4; ++mi)
#pragma unroll
        for (int ni = 0; ni < 4; ++ni)
            acc[mi][ni] = (floatx4){0.f, 0.f, 0.f, 0.f};
    for (int k0 = 0; k0 < 1024; k0 += 64) {
#pragma unroll
        for (int i = 0; i < 4; ++i) {
            int idx = tid + i * 256;
            int row = idx >> 3;
            int col = (idx & 7) << 3;
            const float* sa = &X[(size_t)(m0 + row) * 1024 + k0 + col];
            *(short8*)&Asm[row * 72 + col] = cvt8(*(const float4*)sa, *(const float4*)(sa + 4));
            const float* sb = &W[(size_t)(n0 + row) * 1024 + k0 + col];
            *(short8*)&Bsm[row * 72 + col] = cvt8(*(const float4*)sb, *(const float4*)(sb + 4));
        }
        __syncthreads();
#pragma unroll
        for (int ks = 0; ks < 64; ks += 32) {
            short8 af[4], bfr[4];
#pragma unroll
            for (int mi = 0; mi < 4; ++mi)
                af[mi] = *(const short8*)&Asm[(wr * 64 + mi * 16 + lm) * 72 + ks + g * 8];
#pragma unroll
            for (int ni = 0; ni < 4; ++ni)
                bfr[ni] = *(const short8*)&Bsm[(wc * 64 + ni * 16 + lm) * 72 + ks + g * 8];
#pragma unroll
            for (int mi = 0; mi < 4; ++mi)
#pragma unroll
                for (int ni = 0; ni < 4; ++ni)
                    acc[mi][ni] = __builtin_amdgcn_mfma_f32_16x16x32_bf16(
                        af[mi], bfr[ni], acc[mi][ni], 0, 0, 0);
        }
        __syncthreads();
    }
    float cb[4];
#pragma unroll
    for (int ni = 0; ni < 4; ++ni)
        cb[ni] = ROWBIAS ? 0.f : bias[n0 + wc * 64 + ni * 16 + lm];
#pragma unroll
    for (int mi = 0; mi < 4; ++mi)
#pragma unroll
        for (int r = 0; r < 4; ++r) {
            int rowg = m0 + wr * 64 + mi * 16 + g * 4 + r;
            float rb = ROWBIAS ? bias[rowg] : 0.f;
#pragma unroll
            for (int ni = 0; ni < 4; ++ni) {
                int colg = n0 + wc * 64 + ni * 16 + lm;
                if (PERMN) colg = (colg & ~63) | permtok(colg & 63);
                out[(size_t)rowg * OSTRIDE + colg] =
                    f2bf(acc[mi][ni][r] + (ROWBIAS ? rb : cb[ni]));
            }
        }
}

__global__ __launch_bounds__(256) void qkv_gemm_f(
    const float* __restrict__ xq, const float* __restrict__ xk,
    const float* __restrict__ wq, const float* __restrict__ wk,
    const float* __restrict__ bq, const float* __restrict__ bk,
    unsigned short* __restrict__ q, unsigned short* __restrict__ k) {
    if (blockIdx.z == 0) gemm128_f<false, false, 1024>(xq, wq, bq, q);
    else                 gemm128_f<false, false, 1024>(xk, wk, bk, k);
}

__global__ __launch_bounds__(256) void vt_gemm_f(
    const float* __restrict__ wv, const float* __restrict__ xv,
    const float* __restrict__ bv, unsigned short* __restrict__ VT) {
    gemm128_f<true, true, 4096>(wv, xv, bv, VT);
}

__global__ __launch_bounds__(256) void out_gemm_f(
    const float* __restrict__ wo, const float* __restrict__ bo,
    const unsigned short* __restrict__ ctx, float* __restrict__ out) {
    __shared__ __align__(16) unsigned short Asm[128 * 72];
    __shared__ __align__(16) unsigned short Bsm[128 * 72];
    const int tid = threadIdx.x;
    const int lane = tid & 63;
    const int wv = tid >> 6;
    const int g = lane >> 4;
    const int lm = lane & 15;
    const int wr = wv >> 1;
    const int wc = wv & 1;
    const int m0 = blockIdx.y * 128;
    const int n0 = blockIdx.x * 128;
    floatx4 acc[4][4];
#pragma unroll
    for (int mi = 0; mi < 4; ++mi)
#pragma unroll
        for (int ni = 0; ni < 4; ++ni)
            acc[mi][ni] = (floatx4){0.f, 0.f, 0.f, 0.f};
    for (int k0 = 0; k0 < 1024; k0 += 64) {
#pragma unroll
        for (int i = 0; i < 4; ++i) {
            int idx = tid + i * 256;
            int row = idx >> 3;
            int col = (idx & 7) << 3;
            *(uint4*)&Asm[row * 72 + col] =
                *(const uint4*)&ctx[(size_t)(m0 + row) * 1024 + k0 + col];
            const float* sb = &wo[(size_t)(n0 + row) * 1024 + k0 + col];
            *(short8*)&Bsm[row * 72 + col] = cvt8(*(const float4*)sb, *(const float4*)(sb + 4));
        }
        __syncthreads();
#pragma unroll
        for (int ks = 0; ks < 64; ks += 32) {
            short8 af[4], bfr[4];
#pragma unroll
            for (int mi = 0; mi < 4; ++mi)
                af[mi] = *(const short8*)&Asm[(wr * 64 + mi * 16 + lm) * 72 + ks + g * 8];
#pragma unroll
            for (int ni = 0; ni < 4; ++ni)
                bfr[ni] = *(const short8*)&Bsm[(wc * 64 + ni * 16 + lm) * 72 + ks + g * 8];
#pragma unroll
            for (int mi = 0; mi < 4; ++mi)
#pragma unroll
                for (int ni = 0; ni < 4; ++ni)
                    acc[mi][ni] = __builtin_amdgcn_mfma_f32_16x16x32_bf16(
                        af[mi], bfr[ni], acc[mi][ni], 0, 0, 0);
        }
        __syncthreads();
    }
    float bb[4];
#pragma unroll
    for (int ni = 0; ni < 4; ++ni)
        bb[ni] = bo[n0 + wc * 64 + ni * 16 + lm];
#pragma unroll
    for (int mi = 0; mi < 4; ++mi)
#pragma unroll
        for (int ni = 0; ni < 4; ++ni)
#pragma unroll
            for (int r = 0; r < 4; ++r) {
                int rowg = m0 + wr * 64 + mi * 16 + g * 4 + r;
                int colg = n0 + wc * 64 + ni * 16 + lm;
                out[(size_t)rowg * 1024 + colg] = acc[mi][ni][r] + bb[ni];
            }
}

// ---------------------------------------------------------------------------
// Flash attention (unchanged from r9): no-drain pipeline, two 128-key pairs
// in flight, vmcnt(8)/vmcnt(0) + raw barriers. QBLK=32/wave, exp2 builtin,
// ones-MFMA denominator, s_setprio around MFMA clusters.
// ---------------------------------------------------------------------------
__global__ __launch_bounds__(256) void attn_kernel(
    const unsigned short* __restrict__ Q, const unsigned short* __restrict__ K,
    const unsigned short* __restrict__ VT, unsigned short* __restrict__ CTX) {
    __shared__ __align__(16) unsigned short Ksm[2][128 * 64];   // rows = keys
    __shared__ __align__(16) unsigned short Vtsm[2][128 * 64];  // row = s*64 + feature d

    const int tid = threadIdx.x;
    const int lane = tid & 63;
    const int w = tid >> 6;
    const int g = lane >> 4;
    const int lm = lane & 15;
    const int bh = blockIdx.x;
    const int qt = blockIdx.y;
    const int b = bh >> 4;
    const int h = bh & 15;

    const size_t base = (size_t)b * SEQ * D_MODEL + (size_t)h * DK;
    const size_t vtbase = (size_t)(h * 64) * NTOK + (size_t)b * SEQ;
    const int rs = (lm & 7) << 3;
    const int lr = lane >> 3;
    const int lc = lane & 7;

    union { unsigned u[4]; short8 s; } onev;
    onev.u[0] = 0x3F803F80u; onev.u[1] = 0x3F803F80u;
    onev.u[2] = 0x3F803F80u; onev.u[3] = 0x3F803F80u;

    short8 qf[2][2];
#pragma unroll
    for (int qs = 0; qs < 2; ++qs) {
        const int qrow = qt * 128 + w * 32 + qs * 16 + lm;
#pragma unroll
        for (int t = 0; t < 2; ++t) {
            short8 raw = *(const short8*)&Q[base + (size_t)qrow * D_MODEL + t * 32 + g * 8];
            union { unsigned u[4]; short8 s; } r;
#pragma unroll
            for (int j = 0; j < 4; ++j) {
                float lo = bf2f((unsigned short)raw[2 * j]) * 0.1803368801f;
                float hi = bf2f((unsigned short)raw[2 * j + 1]) * 0.1803368801f;
                r.u[j] = pk2(lo, hi);
            }
            qf[qs][t] = r.s;
        }
    }

    floatx4 Oacc[2][4];
    floatx4 Lacc[2];
#pragma unroll
    for (int qs = 0; qs < 2; ++qs) {
        Lacc[qs] = (floatx4){0.f, 0.f, 0.f, 0.f};
#pragma unroll
        for (int nb = 0; nb < 4; ++nb) Oacc[qs][nb] = (floatx4){0.f, 0.f, 0.f, 0.f};
    }

    // 8 glds per wave per pair: wave w fills LDS rows [w*32, w*32+32)
    auto issue_pair = [&](int pr, int p) {
        const int krow0 = pr * 128;
#pragma unroll
        for (int i = 0; i < 4; ++i) {
            const int r0 = w * 32 + i * 8;
            const int row = r0 + lr;
            const int gcol = (lc ^ (row & 7)) << 3;
            glds16(&K[base + (size_t)(krow0 + row) * D_MODEL + gcol], &Ksm[p][r0 * 64]);
            glds16(&VT[vtbase + (size_t)(row & 63) * NTOK + krow0 + (row >> 6) * 64 + gcol],
                   &Vtsm[p][r0 * 64]);
        }
    };

    const int NP = SEQ / 128;   // 16
    issue_pair(0, 0);           // vm = 8
    issue_pair(1, 1);           // vm = 16
    for (int pr = 0; pr < NP; ++pr) {
        const int p = pr & 1;
        // my pair-pr loads complete (oldest 8 of <=16 outstanding). FIFO vmcnt.
        if (pr + 1 < NP) asm volatile("s_waitcnt vmcnt(8)" ::: "memory");
        else             asm volatile("s_waitcnt vmcnt(0)" ::: "memory");
        // barrier aggregates: every wave has waited its own vmcnt -> pair pr
        // fully in LDS; also orders vs. previous iteration's buffer overwrite.
        __builtin_amdgcn_s_barrier();

#pragma unroll
        for (int s = 0; s < 2; ++s) {
            const unsigned short* Kt = &Ksm[p][s * 4096];
            const unsigned short* Vv = &Vtsm[p][s * 4096];

            float pa[2][4][4];
#pragma unroll
            for (int kb = 0; kb < 4; ++kb) {
                short8 ak0 = *(const short8*)&Kt[(kb * 16 + lm) * 64 + ((0 + g * 8) ^ rs)];
                short8 ak1 = *(const short8*)&Kt[(kb * 16 + lm) * 64 + ((32 + g * 8) ^ rs)];
#pragma unroll
                for (int qs = 0; qs < 2; ++qs) {
                    floatx4 a = (floatx4){0.f, 0.f, 0.f, 0.f};
                    __builtin_amdgcn_s_setprio(1);
                    a = __builtin_amdgcn_mfma_f32_16x16x32_bf16(ak0, qf[qs][0], a, 0, 0, 0);
                    a = __builtin_amdgcn_mfma_f32_16x16x32_bf16(ak1, qf[qs][1], a, 0, 0, 0);
                    __builtin_amdgcn_s_setprio(0);
#pragma unroll
                    for (int r = 0; r < 4; ++r) pa[qs][kb][r] = __builtin_amdgcn_exp2f(a[r]);
                }
            }

#pragma unroll
            for (int cp = 0; cp < 2; ++cp) {
                const int c0 = 2 * cp, c1 = 2 * cp + 1;
                union { unsigned u[4]; short8 s; } ap[2];
#pragma unroll
                for (int qs = 0; qs < 2; ++qs) {
                    ap[qs].u[0] = pk2(pa[qs][c0][0], pa[qs][c0][1]);
                    ap[qs].u[1] = pk2(pa[qs][c0][2], pa[qs][c0][3]);
                    ap[qs].u[2] = pk2(pa[qs][c1][0], pa[qs][c1][1]);
                    ap[qs].u[3] = pk2(pa[qs][c1][2], pa[qs][c1][3]);
                }
                __builtin_amdgcn_s_setprio(1);
#pragma unroll
                for (int nb = 0; nb < 4; ++nb) {
                    const int d = nb * 16 + lm;
                    short8 bv = *(const short8*)&Vv[d * 64 + ((g * 16 + cp * 8) ^ rs)];
                    Oacc[0][nb] = __builtin_amdgcn_mfma_f32_16x16x32_bf16(
                        ap[0].s, bv, Oacc[0][nb], 0, 0, 0);
                    Oacc[1][nb] = __builtin_amdgcn_mfma_f32_16x16x32_bf16(
                        ap[1].s, bv, Oacc[1][nb], 0, 0, 0);
                }
                Lacc[0] = __builtin_amdgcn_mfma_f32_16x16x32_bf16(
                    ap[0].s, onev.s, Lacc[0], 0, 0, 0);
                Lacc[1] = __builtin_amdgcn_mfma_f32_16x16x32_bf16(
                    ap[1].s, onev.s, Lacc[1], 0, 0, 0);
                __builtin_amdgcn_s_setprio(0);
            }
        }

        // all waves done reading buf[p] -> safe to overwrite with pair pr+2.
        __builtin_amdgcn_s_barrier();
        if (pr + 2 < NP) issue_pair(pr + 2, p);
    }

#pragma unroll
    for (int qs = 0; qs < 2; ++qs) {
        float rl[4];
#pragma unroll
        for (int r = 0; r < 4; ++r) rl[r] = 1.0f / Lacc[qs][r];
#pragma unroll
        for (int nb = 0; nb < 4; ++nb) {
#pragma unroll
            for (int r = 0; r < 4; ++r) {
                float val = Oacc[qs][nb][r] * rl[r];
                int srow = qt * 128 + w * 32 + qs * 16 + g * 4 + r;
                CTX[base + (size_t)srow * D_MODEL + nb * 16 + lm] = f2bf(val);
            }
        }
    }
}

extern "C" void kernel_launch(void* const* d_in, const int* in_sizes, int n_in,
                              void* d_out, int out_size, void* d_ws, size_t ws_size,
                              hipStream_t stream) {
    const float* xq = (const float*)d_in[0];
    const float* xk = (const float*)d_in[1];
    const float* xv = (const float*)d_in[2];
    const float* wq = (const float*)d_in[3];
    const float* bq = (const float*)d_in[4];
    const float* wk = (const float*)d_in[5];
    const float* bk = (const float*)d_in[6];
    const float* wv = (const float*)d_in[7];
    const float* bv = (const float*)d_in[8];
    const float* wo = (const float*)d_in[9];
    const float* bo = (const float*)d_in[10];
    float* out = (float*)d_out;

    unsigned short* ws = (unsigned short*)d_ws;

    if (ws_size >= (size_t)68 * 1024 * 1024) {
        // bf16 path: Xb[3*MAT] | Wb[4*WMAT] | Q | K | VT | C
        unsigned short* Xb = ws;
        unsigned short* Wb = ws + (size_t)3 * MAT;
        unsigned short* Qw = Wb + (size_t)4 * WMAT;
        unsigned short* Kw = Qw + (size_t)MAT;
        unsigned short* VTw = Kw + (size_t)MAT;
        unsigned short* Cw = VTw + (size_t)MAT;

        cvt7<<<dim3(2048, 7), 256, 0, stream>>>(xq, xk, xv, wq, wk, wv, wo, ws);
        proj_gemm_b<<<dim3(256, 1, 3), 256, 0, stream>>>(Xb, Wb, bq, bk, bv, Qw, VTw);
        attn_kernel<<<dim3(2 * NH, SEQ / 128), 256, 0, stream>>>(Qw, Kw, VTw, Cw);
        out_gemm_b<<<dim3(8, 64), 256, 0, stream>>>(Cw, Wb + (size_t)3 * WMAT, bo, out);
    } else {
        unsigned short* Qw = ws;
        unsigned short* Kw = ws + (size_t)MAT;
        unsigned short* VTw = ws + (size_t)2 * MAT;
        unsigned short* Cw = ws + (size_t)3 * MAT;
        qkv_gemm_f<<<dim3(8, 32, 2), 256, 0, stream>>>(xq, xk, wq, wk, bq, bk, Qw, Kw);
        vt_gemm_f<<<dim3(32, 8), 256, 0, stream>>>(wv, xv, bv, VTw);
        attn_kernel<<<dim3(2 * NH, SEQ / 128), 256, 0, stream>>>(Qw, Kw, VTw, Cw);
        out_gemm_f<<<dim3(8, 32), 256, 0, stream>>>(wo, bo, Cw, out);
    }
}